// Round 3
// baseline (203.985 us; speedup 1.0000x reference)
//
#include <hip/hip_runtime.h>

#define INV_2PI 0.15915494309189535f

// v_sin_f32 takes REVOLUTIONS: sin(2*pi*x) directly, no range reduction
// (args ~[0,1]). volatile pins sin order -> batches stream back-to-back
// through the trans pipe (~8 cyc/wave64 sin, confirmed by VALUBusy math).
__device__ __forceinline__ float vsin_pinned(float x) {
    float r;
    asm volatile("v_sin_f32 %0, %1" : "=v"(r) : "v"(x));
    return r;
}

// Batched diff_round: N independent sins, then N fmas on long-ready operands.
template <int N>
__device__ __forceinline__ void dround_batch(float* c) {
    float s[N];
#pragma unroll
    for (int i = 0; i < N; ++i) s[i] = vsin_pinned(c[i]);
#pragma unroll
    for (int i = 0; i < N; ++i) c[i] = __builtin_fmaf(-INV_2PI, s[i], c[i]);
}

// Tail of filter_mask_of_interest: eq-combine vs (hb,vb), hdr(eq),
// differentiable_and tree -> m[4] per-pixel mask weight.
__device__ __forceinline__ void filter_tail(float* c, const float* hb,
                                            const float* vb, float* m) {
#pragma unroll
    for (int i = 0; i < 16; ++i) {
        float om = 1.0f - c[i];
        c[i] = __builtin_fmaf(c[i], hb[i & 3], om * vb[i & 3]);
    }
    dround_batch<16>(c); dround_batch<16>(c); dround_batch<16>(c);
    dround_batch<16>(c);
    float p[8];
#pragma unroll
    for (int j = 0; j < 4; ++j) {
        p[2 * j]     = c[4 * j]     * c[4 * j + 1];
        p[2 * j + 1] = c[4 * j + 2] * c[4 * j + 3];
    }
    dround_batch<8>(p);
#pragma unroll
    for (int j = 0; j < 4; ++j) m[j] = p[2 * j] * p[2 * j + 1];
}

struct SideRegs { float i0, i1, i2, i3; float4 idv; };

// Counted waits, never vmcnt(0) in steady state: each stage issues exactly
// 12 vm ops (8 global_load_lds + 4 img dwords), so vmcnt(12) = "everything
// older than the stage I just issued has landed".
#define WAIT12() asm volatile("s_waitcnt vmcnt(12)" ::: "memory")
#define WAIT0()  asm volatile("s_waitcnt vmcnt(0)"  ::: "memory")

typedef __attribute__((address_space(1))) const void gvoid_t;
typedef __attribute__((address_space(3))) void svoid_t;

// Async-DMA stage of one area: mask (4 KB) + alt (4 KB) into the wave's
// private LDS slot via global_load_lds (16 B/lane => 1 KB contiguous per
// instr; 4 back-to-back instrs = 4 KB contiguous per array). Requests stay
// in flight with NO wave-side register destination -> the convoy effect
// (waves stalling in the memory-issue stage) disappears. img + id go to
// registers (small). LDS layout is linear pixel-major: gl_lds writes
// base + lane*16, which is exactly pixel {i*64+lane}'s 4 channels.
__device__ __forceinline__ void stage_area(
        float* sslot, SideRegs& r,
        const float* __restrict__ img, const float* __restrict__ mask,
        const float* __restrict__ mask_alt, const float* __restrict__ mask_id,
        int area, int lane)
{
    area = __builtin_amdgcn_readfirstlane(area);   // SGPR bases
    const float* gm = mask     + (size_t)area * 1024 + lane * 4;
    const float* ga = mask_alt + (size_t)area * 1024 + lane * 4;
#pragma unroll
    for (int i = 0; i < 4; ++i)
        __builtin_amdgcn_global_load_lds((gvoid_t*)(gm + i * 256),
                                         (svoid_t*)(sslot + i * 256),
                                         16, 0, 0);
#pragma unroll
    for (int i = 0; i < 4; ++i)
        __builtin_amdgcn_global_load_lds((gvoid_t*)(ga + i * 256),
                                         (svoid_t*)(sslot + 1024 + i * 256),
                                         16, 0, 0);
    const float* ip = img + (size_t)area * 256 + lane;
    r.i0 = ip[0]; r.i1 = ip[64]; r.i2 = ip[128]; r.i3 = ip[192];
    r.idv = *(const float4*)(mask_id + (size_t)area * 4);   // uniform -> s_load
}

__device__ __forceinline__ void compute_store(
        const float* sslot, const SideRegs& r,
        float* __restrict__ out, float* __restrict__ out_alt,
        int area, int lane)
{
    area = __builtin_amdgcn_readfirstlane(area);
    const size_t base = (size_t)area * 256;

    // ds_read_b128, lane stride 16 B -> 2-way bank aliasing (free).
    const float* sm = sslot + lane * 4;
    float4 q0 = *(const float4*)(sm);
    float4 q1 = *(const float4*)(sm + 256);
    float4 q2 = *(const float4*)(sm + 512);
    float4 q3 = *(const float4*)(sm + 768);
    float4 a0 = *(const float4*)(sm + 1024);
    float4 a1 = *(const float4*)(sm + 1280);
    float4 a2 = *(const float4*)(sm + 1536);
    float4 a3 = *(const float4*)(sm + 1792);

    // Merged first hdr stage: id channels (->hb) + variant-0 mask, one
    // 20-wide sin stream.
    float c0[20] = { r.idv.x, r.idv.y, r.idv.z, r.idv.w,
                     q0.x, q0.y, q0.z, q0.w,  q1.x, q1.y, q1.z, q1.w,
                     q2.x, q2.y, q2.z, q2.w,  q3.x, q3.y, q3.z, q3.w };
    dround_batch<20>(c0); dround_batch<20>(c0); dround_batch<20>(c0);

    float hb[4] = { c0[0], c0[1], c0[2], c0[3] };
    float vb[4];
#pragma unroll
    for (int k = 0; k < 4; ++k) vb[k] = 1.0f - hb[k];

    float m0[4];
    filter_tail(c0 + 4, hb, vb, m0);

    float c1[16] = { a0.x, a0.y, a0.z, a0.w,  a1.x, a1.y, a1.z, a1.w,
                     a2.x, a2.y, a2.z, a2.w,  a3.x, a3.y, a3.z, a3.w };
    dround_batch<16>(c1); dround_batch<16>(c1); dround_batch<16>(c1);
    float m1[4];
    filter_tail(c1, hb, vb, m1);

    // Joint 6-stage butterfly carrying all 4 partial sums.
    float im[4] = { r.i0, r.i1, r.i2, r.i3 };
    float sm0 = 0.f, si0 = 0.f, sm1 = 0.f, si1 = 0.f;
#pragma unroll
    for (int j = 0; j < 4; ++j) {
        sm0 += m0[j]; si0 += m0[j] * im[j];
        sm1 += m1[j]; si1 += m1[j] * im[j];
    }
#pragma unroll
    for (int off = 32; off; off >>= 1) {
        sm0 += __shfl_xor(sm0, off, 64);
        si0 += __shfl_xor(si0, off, 64);
        sm1 += __shfl_xor(sm1, off, 64);
        si1 += __shfl_xor(si1, off, 64);
    }

    // Guard 0/0: m >= 0, so sm==0 implies all m==0 -> output 0.
    const float mean0 = (sm0 > 0.f) ? (si0 / sm0) : 0.f;
    const float mean1 = (sm1 > 0.f) ? (si1 / sm1) : 0.f;

    float* d0 = out     + base + lane;
    float* d1 = out_alt + base + lane;
#pragma unroll
    for (int k = 0; k < 4; ++k) {
        d0[64 * k] = m0[k] * mean0;   // 256 B/instr, coalesced
        d1[64 * k] = m1[k] * mean1;
    }
}

// Each wave owns APW CONSECUTIVE areas (contiguous 32 KB read streams per
// array) and runs a barrier-free LDS double-buffer: DMA-stage area t+1,
// counted-wait, compute area t from LDS. No __syncthreads anywhere, so no
// compiler-forced vmcnt(0) drains (the m97 stall mechanism).
__global__ __launch_bounds__(256) void De_conv_areas_kernel(
    const float* __restrict__ img,       // [A,256,1] f32
    const float* __restrict__ mask,      // [A,256,4] f32
    const float* __restrict__ mask_alt,  // [A,256,4] f32
    const float* __restrict__ mask_id,   // [A,4]     f32
    float* __restrict__ out,             // [A,256]   f32
    float* __restrict__ out_alt,         // [A,256]   f32
    int n_areas, int apw)
{
    // 4 waves x 2 slots x (mask 1024 + alt 1024 floats) = 64 KB/block,
    // 2 blocks/CU (128 KB of 160 KB LDS).
    __shared__ __align__(16) float lds[4][2][2048];

    const int lane = threadIdx.x & 63;
    const int wv   = threadIdx.x >> 6;

    // XCD-aware chunked swizzle (gridDim.x % 8 == 0 -> bijective): each
    // XCD's L2 sees one contiguous region of the area space.
    int bid = blockIdx.x;
    int sbid = (gridDim.x % 8 == 0)
             ? ((bid & 7) * (gridDim.x >> 3) + (bid >> 3)) : bid;

    const int w  = sbid * 4 + wv;
    const int a0 = w * apw;
    if (a0 >= n_areas) return;
    const int end = (a0 + apw < n_areas) ? (a0 + apw) : n_areas;

    float* slotA = &lds[wv][0][0];
    float* slotB = &lds[wv][1][0];
    SideRegs rA, rB;

    stage_area(slotA, rA, img, mask, mask_alt, mask_id, a0, lane);

    for (int t = a0;; t += 2) {
        const bool n1 = (t + 1 < end);
        if (n1) { stage_area(slotB, rB, img, mask, mask_alt, mask_id, t + 1, lane); WAIT12(); }
        else    { WAIT0(); }
        compute_store(slotA, rA, out, out_alt, t, lane);
        if (!n1) break;

        const bool n2 = (t + 2 < end);
        if (n2) { stage_area(slotA, rA, img, mask, mask_alt, mask_id, t + 2, lane); WAIT12(); }
        else    { WAIT0(); }
        compute_store(slotB, rB, out, out_alt, t + 1, lane);
        if (!n2) break;
    }
}

extern "C" void kernel_launch(void* const* d_in, const int* in_sizes, int n_in,
                              void* d_out, int out_size, void* d_ws, size_t ws_size,
                              hipStream_t stream) {
    // setup_inputs() order (all float32 per reference):
    // 0: resized_image      [B,N,16,16,1]
    // 1: mask_combined      [B,N,16,16,4]
    // 2: mask_combined_alt  [B,N,16,16,4]
    // 3: initial_mask_id    [B,N,4]
    // 4: mask_new_bi_channel (unused)
    // 5: mask_index          (unused)
    const float* img      = (const float*)d_in[0];
    const float* mask     = (const float*)d_in[1];
    const float* mask_alt = (const float*)d_in[2];
    const float* mask_id  = (const float*)d_in[3];

    const int n_areas = out_size / 512;             // B*N = 16384
    float* out     = (float*)d_out;
    float* out_alt = out + (size_t)n_areas * 256;

    // 512 blocks (2/CU at 64 KB LDS) x 4 waves = 2048 waves;
    // 8 consecutive areas per wave (16384 = 2048 * 8 exactly).
    const int n_waves = 2048;
    const int apw = (n_areas + n_waves - 1) / n_waves;
    const int blocks = 512;
    De_conv_areas_kernel<<<blocks, 256, 0, stream>>>(
        img, mask, mask_alt, mask_id, out, out_alt, n_areas, apw);
}

// Round 4
// 192.224 us; speedup vs baseline: 1.0612x; 1.0612x over previous
//
#include <hip/hip_runtime.h>

#define INV_2PI 0.15915494309189535f

// v_sin_f32 takes REVOLUTIONS: sin(2*pi*x) directly, no range reduction
// (all dround inputs provably in [0,1]). volatile pins sin order so a
// batch streams back-to-back through the trans pipe.
__device__ __forceinline__ float vsin_pinned(float x) {
    float r;
    asm volatile("v_sin_f32 %0, %1" : "=v"(r) : "v"(x));
    return r;
}

// Polynomial diff_round on the FULL-RATE VALU pipe (not trans).
// All dround inputs x are in [0,1] (dround maps [0,1]->[0,1], eq is a
// convex blend), so r = x-0.5 in [-.5,.5] with NO rounding step, and
// sin(2*pi*x) = -sin(2*pi*r):
//   dround(x) = x - sin(2pi x)/2pi = x + r*h(r^2),  h = sin(2pi r)/(2pi r)
// 8-term Taylor in s=r^2 (alternating series): |err| <= 1.3e-7 over the
// whole range (checked: h(0.25)=0 -> dround(1)=1; f(0.25)=1/2pi exact).
// 10 VALU ops vs 1 trans + 1 fma -- trades pipe occupancy, not work count.
__device__ __forceinline__ float dround_poly(float x) {
    const float r = x - 0.5f;
    const float s = r * r;
    float h = __builtin_fmaf(s, -0.1142929f, 0.6079689f);
    h = __builtin_fmaf(s, h, -2.4023840f);
    h = __builtin_fmaf(s, h, 6.6938470f);
    h = __builtin_fmaf(s, h, -12.2081150f);
    h = __builtin_fmaf(s, h, 12.9878788f);
    h = __builtin_fmaf(s, h, -6.5797363f);
    h = __builtin_fmaf(s, h, 1.0f);
    return __builtin_fmaf(r, h, x);
}

// Hybrid batch: NS elements through the trans pipe (v_sin), NP elements
// through the VALU pipe (poly). The poly block is ~NP*10 independent
// full-rate ops that fill the shadow of the trans burst -- the wave always
// has issueable work while sins are in flight, and total trans-pipe
// pressure is halved. Element->path assignment is static (index < NS),
// so each value sees a consistent path across stages.
template <int NS, int NP>
__device__ __forceinline__ void dround_hyb(float* c) {
    float sn[NS];
#pragma unroll
    for (int i = 0; i < NS; ++i) sn[i] = vsin_pinned(c[i]);
#pragma unroll
    for (int j = 0; j < NP; ++j) c[NS + j] = dround_poly(c[NS + j]);
#pragma unroll
    for (int i = 0; i < NS; ++i) c[i] = __builtin_fmaf(-INV_2PI, sn[i], c[i]);
}

// One wave (64 lanes) per (area, mask-variant); lane owns 4 contiguous
// pixels (16 mask channels) live in c[16]. Memory structure identical to
// the best-measured round (R0): the only change is hybrid drounds.
__global__ __launch_bounds__(256) void De_conv_areas_kernel(
    const float* __restrict__ img,       // [A,256,1] f32
    const float* __restrict__ mask,      // [A,256,4] f32
    const float* __restrict__ mask_alt,  // [A,256,4] f32
    const float* __restrict__ mask_id,   // [A,4]     f32
    float* __restrict__ out,             // [A,256]   f32  (output 0)
    float* __restrict__ out_alt,         // [A,256]   f32  (output 1)
    int n_areas)
{
    const int lane = threadIdx.x & 63;
    const int w    = blockIdx.x * (blockDim.x >> 6) + (threadIdx.x >> 6);
    const int area  = w >> 1;
    const int which = w & 1;                 // 0 -> mask/out, 1 -> mask_alt/out_alt
    if (area >= n_areas) return;

    const float* msk = which ? mask_alt : mask;   // wave-uniform select
    float*       dst = which ? out_alt  : out;

    const size_t pix = (size_t)area * 256 + (size_t)lane * 4;

    // Issue all VMEM up front; loads in flight while hb is computed.
    float4 idv = *(const float4*)(mask_id + (size_t)area * 4);
    const float4* mp = (const float4*)(msk + pix * 4);
    float4 p0 = mp[0], p1 = mp[1], p2 = mp[2], p3 = mp[3];
    float4 im = *(const float4*)(img + pix);

    // Per-area id (wave-uniform): harder_diff_round, hybrid 2 sin + 2 poly.
    float hb[4] = { idv.x, idv.y, idv.z, idv.w };
    dround_hyb<2, 2>(hb); dround_hyb<2, 2>(hb); dround_hyb<2, 2>(hb);
    float vb[4];
#pragma unroll
    for (int k = 0; k < 4; ++k) vb[k] = 1.0f - hb[k];

    float c[16] = { p0.x, p0.y, p0.z, p0.w,  p1.x, p1.y, p1.z, p1.w,
                    p2.x, p2.y, p2.z, p2.w,  p3.x, p3.y, p3.z, p3.w };

    // harder_diff_round(mask channels): 3 hybrid batches of 8 sin + 8 poly.
    dround_hyb<8, 8>(c); dround_hyb<8, 8>(c); dround_hyb<8, 8>(c);

    // differentiable_eq combine: t = a*hb + (1-a)*vb   (full-rate VALU)
#pragma unroll
    for (int i = 0; i < 16; ++i) {
        float om = 1.0f - c[i];
        c[i] = __builtin_fmaf(c[i], hb[i & 3], om * vb[i & 3]);
    }

    // harder_diff_round(eq): 3 hybrid batches.
    dround_hyb<8, 8>(c); dround_hyb<8, 8>(c); dround_hyb<8, 8>(c);

    // differentiable_and tree: dround each channel once, pairwise products,
    // dround the partials, final product.
    dround_hyb<8, 8>(c);
    float p[8];
#pragma unroll
    for (int j = 0; j < 4; ++j) {
        p[2*j]   = c[4*j]   * c[4*j+1];
        p[2*j+1] = c[4*j+2] * c[4*j+3];
    }
    dround_hyb<4, 4>(p);

    float imv[4] = { im.x, im.y, im.z, im.w };
    float m[4];
    float sm = 0.f, si = 0.f;
#pragma unroll
    for (int j = 0; j < 4; ++j) {
        m[j] = p[2*j] * p[2*j+1];
        sm += m[j]; si += m[j] * imv[j];
    }

    // Wave-wide butterfly reduction (64 lanes) for num/den.
#pragma unroll
    for (int off = 32; off; off >>= 1) {
        sm += __shfl_xor(sm, off, 64);
        si += __shfl_xor(si, off, 64);
    }

    // Guard 0/0: m >= 0 sums, so sm==0 implies every m==0 -> output 0.
    const float mean = (sm > 0.f) ? (si / sm) : 0.f;

    float4 o;
    o.x = m[0] * mean; o.y = m[1] * mean; o.z = m[2] * mean; o.w = m[3] * mean;
    *(float4*)(dst + pix) = o;                               // 16 B/lane, coalesced
}

extern "C" void kernel_launch(void* const* d_in, const int* in_sizes, int n_in,
                              void* d_out, int out_size, void* d_ws, size_t ws_size,
                              hipStream_t stream) {
    // setup_inputs() order (all float32 per reference):
    // 0: resized_image      [B,N,16,16,1]
    // 1: mask_combined      [B,N,16,16,4]
    // 2: mask_combined_alt  [B,N,16,16,4]
    // 3: initial_mask_id    [B,N,4]
    // 4: mask_new_bi_channel (unused)
    // 5: mask_index          (unused)
    const float* img      = (const float*)d_in[0];
    const float* mask     = (const float*)d_in[1];
    const float* mask_alt = (const float*)d_in[2];
    const float* mask_id  = (const float*)d_in[3];

    const int n_areas = out_size / 512;             // B*N = 16384
    float* out     = (float*)d_out;
    float* out_alt = out + (size_t)n_areas * 256;

    // 2 waves per area (one per mask variant), 4 waves per 256-thread block.
    const int n_waves = n_areas * 2;
    const int waves_per_block = 4;
    const int blocks = (n_waves + waves_per_block - 1) / waves_per_block;
    De_conv_areas_kernel<<<blocks, 256, 0, stream>>>(
        img, mask, mask_alt, mask_id, out, out_alt, n_areas);
}

// Round 6
// 191.259 us; speedup vs baseline: 1.0665x; 1.0050x over previous
//
#include <hip/hip_runtime.h>

#define INV_2PI 0.15915494309189535f

// v_sin_f32 takes REVOLUTIONS: sin(2*pi*x) directly, no range reduction
// (all dround inputs provably in [0,1]). volatile pins sin order so a
// batch streams back-to-back through the trans pipe.
__device__ __forceinline__ float vsin_pinned(float x) {
    float r;
    asm volatile("v_sin_f32 %0, %1" : "=v"(r) : "v"(x));
    return r;
}

// Batched diff_round: N independent sins issue back-to-back, then N fmas
// whose operands are long-ready.
template <int N>
__device__ __forceinline__ void dround_batch(float* c) {
    float s[N];
#pragma unroll
    for (int i = 0; i < N; ++i) s[i] = vsin_pinned(c[i]);
#pragma unroll
    for (int i = 0; i < N; ++i) c[i] = __builtin_fmaf(-INV_2PI, s[i], c[i]);
}

// Tail of filter_mask_of_interest: eq-combine vs (hb,vb), hdr(eq),
// differentiable_and tree -> m[4] per-pixel mask weight.
__device__ __forceinline__ void filter_tail(float* c, const float* hb,
                                            const float* vb, float* m) {
#pragma unroll
    for (int i = 0; i < 16; ++i) {
        float om = 1.0f - c[i];
        c[i] = __builtin_fmaf(c[i], hb[i & 3], om * vb[i & 3]);
    }
    dround_batch<16>(c); dround_batch<16>(c); dround_batch<16>(c);
    dround_batch<16>(c);
    float p[8];
#pragma unroll
    for (int j = 0; j < 4; ++j) {
        p[2 * j]     = c[4 * j]     * c[4 * j + 1];
        p[2 * j + 1] = c[4 * j + 2] * c[4 * j + 3];
    }
    dround_batch<8>(p);
#pragma unroll
    for (int j = 0; j < 4; ++j) m[j] = p[2 * j] * p[2 * j + 1];
}

// Minimal-traffic structure: ONE wave per area computes BOTH variants.
// Lane owns 4 CONTIGUOUS pixels (R0's layout -> all-float4 accesses):
//   12 vmem requests/area (4+4 mask float4, 1 img float4, 2 store float4)
//   vs 14 for the two-wave split (img + hb duplicated) and 21 for the
//   strided one-wave split. 185 MB/dispatch total, the algorithmic floor.
// Load order mask -> img -> alt: compiler's counted waitcnt for the mask
// regs leaves img+alt in flight under variant-0's ~1.6k cycles of sins.
__global__ __launch_bounds__(256) void De_conv_areas_kernel(
    const float* __restrict__ img,       // [A,256,1] f32
    const float* __restrict__ mask,      // [A,256,4] f32
    const float* __restrict__ mask_alt,  // [A,256,4] f32
    const float* __restrict__ mask_id,   // [A,4]     f32
    float* __restrict__ out,             // [A,256]   f32  (output 0)
    float* __restrict__ out_alt,         // [A,256]   f32  (output 1)
    int n_areas)
{
    const int lane = threadIdx.x & 63;
    int area = blockIdx.x * (blockDim.x >> 6) + (threadIdx.x >> 6);
    if (area >= n_areas) return;
    area = __builtin_amdgcn_readfirstlane(area);   // wave-uniform -> SGPR bases

    const size_t pix = (size_t)area * 256 + (size_t)lane * 4;

    // Issue all VMEM up front, in consumption order.
    const float4* mp = (const float4*)(mask     + pix * 4);
    const float4* ap = (const float4*)(mask_alt + pix * 4);
    float4 q0 = mp[0], q1 = mp[1], q2 = mp[2], q3 = mp[3];
    float4 im = *(const float4*)(img + pix);
    float4 a0 = ap[0], a1 = ap[1], a2 = ap[2], a3 = ap[3];
    float4 idv = *(const float4*)(mask_id + (size_t)area * 4);  // uniform

    // Per-area id (computed ONCE for both variants): hdr, merged with the
    // variant-0 mask channels into one 20-wide sin stream.
    float c0[20] = { idv.x, idv.y, idv.z, idv.w,
                     q0.x, q0.y, q0.z, q0.w,  q1.x, q1.y, q1.z, q1.w,
                     q2.x, q2.y, q2.z, q2.w,  q3.x, q3.y, q3.z, q3.w };
    dround_batch<20>(c0); dround_batch<20>(c0); dround_batch<20>(c0);

    float hb[4] = { c0[0], c0[1], c0[2], c0[3] };
    float vb[4];
#pragma unroll
    for (int k = 0; k < 4; ++k) vb[k] = 1.0f - hb[k];

    float m0[4];
    filter_tail(c0 + 4, hb, vb, m0);

    // Variant 1: alt regs landed ~1.6k cycles ago.
    float c1[16] = { a0.x, a0.y, a0.z, a0.w,  a1.x, a1.y, a1.z, a1.w,
                     a2.x, a2.y, a2.z, a2.w,  a3.x, a3.y, a3.z, a3.w };
    dround_batch<16>(c1); dround_batch<16>(c1); dround_batch<16>(c1);
    float m1[4];
    filter_tail(c1, hb, vb, m1);

    // Joint 6-stage butterfly carrying all 4 partial sums.
    float imv[4] = { im.x, im.y, im.z, im.w };
    float sm0 = 0.f, si0 = 0.f, sm1 = 0.f, si1 = 0.f;
#pragma unroll
    for (int j = 0; j < 4; ++j) {
        sm0 += m0[j]; si0 += m0[j] * imv[j];
        sm1 += m1[j]; si1 += m1[j] * imv[j];
    }
#pragma unroll
    for (int off = 32; off; off >>= 1) {
        sm0 += __shfl_xor(sm0, off, 64);
        si0 += __shfl_xor(si0, off, 64);
        sm1 += __shfl_xor(sm1, off, 64);
        si1 += __shfl_xor(si1, off, 64);
    }

    // Guard 0/0: m >= 0, so sm==0 implies all m==0 -> output 0.
    const float mean0 = (sm0 > 0.f) ? (si0 / sm0) : 0.f;
    const float mean1 = (sm1 > 0.f) ? (si1 / sm1) : 0.f;

    float4 o0, o1;
    o0.x = m0[0] * mean0; o0.y = m0[1] * mean0;
    o0.z = m0[2] * mean0; o0.w = m0[3] * mean0;
    o1.x = m1[0] * mean1; o1.y = m1[1] * mean1;
    o1.z = m1[2] * mean1; o1.w = m1[3] * mean1;
    *(float4*)(out     + pix) = o0;              // 16 B/lane, coalesced
    *(float4*)(out_alt + pix) = o1;
}

extern "C" void kernel_launch(void* const* d_in, const int* in_sizes, int n_in,
                              void* d_out, int out_size, void* d_ws, size_t ws_size,
                              hipStream_t stream) {
    // setup_inputs() order (all float32 per reference):
    // 0: resized_image      [B,N,16,16,1]
    // 1: mask_combined      [B,N,16,16,4]
    // 2: mask_combined_alt  [B,N,16,16,4]
    // 3: initial_mask_id    [B,N,4]
    // 4: mask_new_bi_channel (unused)
    // 5: mask_index          (unused)
    const float* img      = (const float*)d_in[0];
    const float* mask     = (const float*)d_in[1];
    const float* mask_alt = (const float*)d_in[2];
    const float* mask_id  = (const float*)d_in[3];

    const int n_areas = out_size / 512;             // B*N = 16384
    float* out     = (float*)d_out;
    float* out_alt = out + (size_t)n_areas * 256;

    // One wave per area (both variants), 4 waves per 256-thread block.
    const int waves_per_block = 4;
    const int blocks = (n_areas + waves_per_block - 1) / waves_per_block;
    De_conv_areas_kernel<<<blocks, 256, 0, stream>>>(
        img, mask, mask_alt, mask_id, out, out_alt, n_areas);
}